// Round 8
// baseline (396.509 us; speedup 1.0000x reference)
//
#include <hip/hip_runtime.h>
#include <hip/hip_bf16.h>

#define VOCAB 50257
#define NB    2048
#define NE    128
#define NCH   393              // ceil(VOCAB/128)  (LSE pass chunking)
#define NWG   (NCH * (NB/128)) // 6288 = 8 * 786
#define NFLAT 1280             // flat-scan blocks in k_prep
#define NTR   ((VOCAB + 63) / 64) // 786 transpose blocks
#define OCH   99               // ceil(VOCAB/512)  (OUT pass chunking)
#define ORG   (NB / 32)        // 64 row groups
#define ONWG  (OCH * ORG)      // 6336 = 8 * 792

typedef __bf16 bf16x8 __attribute__((ext_vector_type(8)));
typedef float  f32x4  __attribute__((ext_vector_type(4)));

// ---------------- fused prep: flat find (blocks 0..1279) | transpose (blocks 1280..2065) ----------------
__global__ __launch_bounds__(256) void k_prep(const float* __restrict__ oh, int* __restrict__ idx,
                                              const float* __restrict__ w2, __hip_bfloat16* __restrict__ w2T) {
  __shared__ __hip_bfloat16 tile[64][130];
  if (blockIdx.x < NFLAT) {
    // ---- flat coalesced scan of the whole one_hot, no divergence, no tail ----
    const float4* ohv = reinterpret_cast<const float4*>(oh);
    const long n4 = ((long)NB * VOCAB) >> 2;
    const long stride = (long)NFLAT * 256;
    for (long i = blockIdx.x * 256 + threadIdx.x; i < n4; i += stride) {
      float4 v = ohv[i];
      if (v.x != 0.f || v.y != 0.f || v.z != 0.f || v.w != 0.f) {
        long j = i << 2;
        if (v.x != 0.f) { long p = j;     int b = (int)(p / VOCAB); idx[b] = (int)(p - (long)b * VOCAB); }
        if (v.y != 0.f) { long p = j + 1; int b = (int)(p / VOCAB); idx[b] = (int)(p - (long)b * VOCAB); }
        if (v.z != 0.f) { long p = j + 2; int b = (int)(p / VOCAB); idx[b] = (int)(p - (long)b * VOCAB); }
        if (v.w != 0.f) { long p = j + 3; int b = (int)(p / VOCAB); idx[b] = (int)(p - (long)b * VOCAB); }
      }
    }
  } else {
    // ---- transpose: w2 [128][V] f32 -> w2T [V][128] bf16 (identical to r6) ----
    const int v0 = (blockIdx.x - NFLAT) * 64;
    const int tv = threadIdx.x & 63;
    const int te = threadIdx.x >> 6;   // 0..3
    const int v  = v0 + tv;
#pragma unroll
    for (int e0 = 0; e0 < NE; e0 += 4) {
      int e = e0 + te;
      float val = (v < VOCAB) ? w2[(long)e * VOCAB + v] : 0.f;
      tile[tv][e] = __float2bfloat16(val);
    }
    __syncthreads();
#pragma unroll
    for (int it = 0; it < 16; ++it) {
      int f  = it * 256 + threadIdx.x;
      int r  = f >> 6;
      int c2 = f & 63;
      int vv = v0 + r;
      if (vv < VOCAB) {
        ushort2 p;
        p.x = *reinterpret_cast<const unsigned short*>(&tile[r][2 * c2]);
        p.y = *reinterpret_cast<const unsigned short*>(&tile[r][2 * c2 + 1]);
        reinterpret_cast<ushort2*>(w2T + (long)vv * NE)[c2] = p;
      }
    }
  }
}

// ---------------- gather: z1[b] = bf16(w1[idx[b]]) ----------------
__global__ void k_gather(const float* __restrict__ w1, const int* __restrict__ idx,
                         __hip_bfloat16* __restrict__ z1) {
  int t = blockIdx.x * blockDim.x + threadIdx.x;   // NB*NE threads
  int b = t >> 7, e = t & 127;
  z1[t] = __float2bfloat16(w1[(long)idx[b] * NE + e]);
}

// ---------------- LSE GEMM (128x128 tiles, operand-swapped; identical to r6) ----------------
__global__ __launch_bounds__(256) void k_lsegemm(
    const __hip_bfloat16* __restrict__ z1,
    const __hip_bfloat16* __restrict__ w2T,
    float* __restrict__ pmax, float* __restrict__ psum) {
  const int bid = blockIdx.x;
  const int g = (bid & 7) * (NWG / 8) + (bid >> 3);
  const int chunk = g >> 4;
  const int rowg  = g & 15;
  const int lane = threadIdx.x & 63;
  const int wave = threadIdx.x >> 6;
  const int wm = wave >> 1, wn = wave & 1;
  const int l15 = lane & 15, lhi = lane >> 4;
  const int row0 = rowg * 128 + wm * 64;
  const int col0 = chunk * 128 + wn * 64;

  bf16x8 bz[4][4];
  {
    const __hip_bfloat16* zp = z1 + (row0 + l15) * NE + lhi * 8;
#pragma unroll
    for (int ri = 0; ri < 4; ++ri)
#pragma unroll
      for (int kb = 0; kb < 4; ++kb)
        bz[ri][kb] = *reinterpret_cast<const bf16x8*>(zp + ri * 16 * NE + kb * 32);
  }

  f32x4 acc[4][4];
#pragma unroll
  for (int vi = 0; vi < 4; ++vi)
#pragma unroll
    for (int ri = 0; ri < 4; ++ri)
      acc[vi][ri] = (f32x4){0.f, 0.f, 0.f, 0.f};

#pragma unroll
  for (int vi = 0; vi < 4; ++vi) {
    int col  = col0 + vi * 16 + l15;
    int colc = col < VOCAB ? col : VOCAB - 1;
    const __hip_bfloat16* wp = w2T + colc * NE + lhi * 8;
    bf16x8 aw[4];
#pragma unroll
    for (int kb = 0; kb < 4; ++kb)
      aw[kb] = *reinterpret_cast<const bf16x8*>(wp + kb * 32);
#pragma unroll
    for (int ri = 0; ri < 4; ++ri)
#pragma unroll
      for (int kb = 0; kb < 4; ++kb)
        acc[vi][ri] = __builtin_amdgcn_mfma_f32_16x16x32_bf16(aw[kb], bz[ri][kb], acc[vi][ri], 0, 0, 0);
  }

  __shared__ float sm[2][128];
  __shared__ float ss[2][128];
#pragma unroll
  for (int ri = 0; ri < 4; ++ri) {
    float v[16];
    float m = -INFINITY;
#pragma unroll
    for (int vi = 0; vi < 4; ++vi)
#pragma unroll
      for (int r = 0; r < 4; ++r) {
        int col = col0 + vi * 16 + lhi * 4 + r;
        float x = (col < VOCAB) ? acc[vi][ri][r] : -INFINITY;
        v[vi * 4 + r] = x;
        m = fmaxf(m, x);
      }
    m = fmaxf(m, __shfl_xor(m, 16));
    m = fmaxf(m, __shfl_xor(m, 32));
    float s = 0.f;
#pragma unroll
    for (int t = 0; t < 16; ++t) s += __expf(v[t] - m);
    s += __shfl_xor(s, 16);
    s += __shfl_xor(s, 32);
    if (lhi == 0) {
      int lr = wm * 64 + ri * 16 + l15;
      sm[wn][lr] = m;
      ss[wn][lr] = s;
    }
  }
  __syncthreads();
  if (threadIdx.x < 128) {
    int r = threadIdx.x;
    float m0 = sm[0][r], m1 = sm[1][r];
    float s0 = ss[0][r], s1 = ss[1][r];
    float M = fmaxf(m0, m1);
    float S = s0 * __expf(m0 - M) + s1 * __expf(m1 - M);
    int o = chunk * NB + rowg * 128 + r;
    pmax[o] = M;
    psum[o] = S;
  }
}

// ---------------- two-stage chunk-partial merge -> lse[b] ----------------
__global__ void k_lse_part(const float* __restrict__ pmax, const float* __restrict__ psum,
                           float* __restrict__ m2, float* __restrict__ s2) {
  int b  = blockIdx.x * 256 + threadIdx.x;
  int cg = blockIdx.y;
  int c0 = cg * 50, c1 = (c0 + 50 < NCH) ? c0 + 50 : NCH;
  float M = -INFINITY;
  for (int c = c0; c < c1; ++c) M = fmaxf(M, pmax[c * NB + b]);
  float S = 0.f;
  for (int c = c0; c < c1; ++c) S += psum[c * NB + b] * __expf(pmax[c * NB + b] - M);
  m2[cg * NB + b] = M;
  s2[cg * NB + b] = S;
}

__global__ void k_lse_final(const float* __restrict__ m2, const float* __restrict__ s2,
                            float* __restrict__ lse) {
  int b = blockIdx.x * 256 + threadIdx.x;
  float M = -INFINITY;
#pragma unroll
  for (int g = 0; g < 8; ++g) M = fmaxf(M, m2[g * NB + b]);
  float S = 0.f;
#pragma unroll
  for (int g = 0; g < 8; ++g) S += s2[g * NB + b] * __expf(m2[g * NB + b] - M);
  lse[b] = M + __logf(S);
}

// ---------------- OUT GEMM: 32-row x 512-col flat tiles, direct stores (identical to r6) ----------------
__global__ __launch_bounds__(256) void k_out(
    const __hip_bfloat16* __restrict__ z1,
    const __hip_bfloat16* __restrict__ w2T,
    const float* __restrict__ lse,
    float* __restrict__ out) {
  const int bid = blockIdx.x;
  const int g = (bid & 7) * (ONWG / 8) + (bid >> 3);   // XCD chunk-major
  const int chunk = g / ORG;          // 0..98 (512-col chunk)
  const int rowg  = g % ORG;          // 0..63 (32-row group)
  const int lane = threadIdx.x & 63;
  const int wave = threadIdx.x >> 6;  // 0..3 : col quarters
  const int l15 = lane & 15, lhi = lane >> 4;
  const int row0 = rowg * 32;
  const int col0 = chunk * 512 + wave * 128;

  bf16x8 bz[2][4];
  {
    const __hip_bfloat16* zp = z1 + (row0 + l15) * NE + lhi * 8;
#pragma unroll
    for (int ri = 0; ri < 2; ++ri)
#pragma unroll
      for (int kb = 0; kb < 4; ++kb)
        bz[ri][kb] = *reinterpret_cast<const bf16x8*>(zp + ri * 16 * NE + kb * 32);
  }

  f32x4 acc[8][2];
#pragma unroll
  for (int vi = 0; vi < 8; ++vi)
#pragma unroll
    for (int ri = 0; ri < 2; ++ri)
      acc[vi][ri] = (f32x4){0.f, 0.f, 0.f, 0.f};

#pragma unroll
  for (int vi = 0; vi < 8; ++vi) {
    int col  = col0 + vi * 16 + l15;
    int colc = col < VOCAB ? col : VOCAB - 1;
    const __hip_bfloat16* wp = w2T + colc * NE + lhi * 8;
    bf16x8 aw[4];
#pragma unroll
    for (int kb = 0; kb < 4; ++kb)
      aw[kb] = *reinterpret_cast<const bf16x8*>(wp + kb * 32);
#pragma unroll
    for (int ri = 0; ri < 2; ++ri)
#pragma unroll
      for (int kb = 0; kb < 4; ++kb)
        acc[vi][ri] = __builtin_amdgcn_mfma_f32_16x16x32_bf16(aw[kb], bz[ri][kb], acc[vi][ri], 0, 0, 0);
  }

  float lsev[2] = {lse[row0 + l15], lse[row0 + 16 + l15]};
#pragma unroll
  for (int ri = 0; ri < 2; ++ri) {
    long obase = (long)(row0 + ri * 16 + l15) * VOCAB;
#pragma unroll
    for (int vi = 0; vi < 8; ++vi) {       // vi inner: consecutive 64B of same rows
      int col = col0 + vi * 16 + lhi * 4;
      f32x4 v = acc[vi][ri] - lsev[ri];
      if (col + 3 < VOCAB) {
        *reinterpret_cast<f32x4*>(out + obase + col) = v;
      } else {
#pragma unroll
        for (int r = 0; r < 4; ++r)
          if (col + r < VOCAB) out[obase + col + r] = v[r];
      }
    }
  }
}

extern "C" void kernel_launch(void* const* d_in, const int* in_sizes, int n_in,
                              void* d_out, int out_size, void* d_ws, size_t ws_size,
                              hipStream_t stream) {
  const float* one_hot = (const float*)d_in[0];
  const float* w1      = (const float*)d_in[1];
  const float* w2      = (const float*)d_in[2];
  float* out = (float*)d_out;

  char* ws = (char*)d_ws;
  int*            idx  = (int*)ws;                       // 8 KB
  __hip_bfloat16* z1   = (__hip_bfloat16*)(ws + 8192);   // 512 KB
  __hip_bfloat16* w2T  = (__hip_bfloat16*)(ws + 532480); // 12.87 MB
  float*          pmax = (float*)(ws + 13398272);        // 3.22 MB
  float*          psum = (float*)(ws + 16617728);        // 3.22 MB
  float*          m2   = (float*)(ws + 19837184);        // 64 KB
  float*          s2   = (float*)(ws + 19902720);        // 64 KB
  float*          lse  = (float*)(ws + 19968256);        // 8 KB

  k_prep<<<NFLAT + NTR, 256, 0, stream>>>(one_hot, idx, w2, w2T);
  k_gather<<<NB * NE / 256, 256, 0, stream>>>(w1, idx, z1);
  k_lsegemm<<<NWG, 256, 0, stream>>>(z1, w2T, pmax, psum);
  k_lse_part<<<dim3(NB / 256, 8), 256, 0, stream>>>(pmax, psum, m2, s2);
  k_lse_final<<<NB / 256, 256, 0, stream>>>(m2, s2, lse);
  k_out<<<ONWG, 256, 0, stream>>>(z1, w2T, lse, out);
}